// Round 1
// 90.308 us; speedup vs baseline: 1.0412x; 1.0412x over previous
//
#include <hip/hip_runtime.h>

// GlobalAttentionModule collapses algebraically:
//   weight = softmax(score, axis=-1)  =>  sum_j weight[b,c,i,j] == 1
//   out = (v[:,:,:,None] * weight).sum(-1) = v
// where v = relu(GroupNorm32(Wv @ feat + bv, gn_v_g, gn_v_b)).
// Only inputs 0 (feat), 5 (Wv), 6 (bv), 7 (gn_v_g), 8 (gn_v_b) matter.
//
// Perf note: the harness re-poisons the 268 MB workspace inside the timed
// window (2 x ~40.5 us fillBuffer at 83% HBM peak) — that floor is not ours.
// The controllable slice was ~13 us: a 64-block kernel (25% of CUs, 1
// wave/SIMD) latency-bound on 128 serial L2 loads. Split the GroupNorm
// reduction across 4 blocks per group via workspace partials -> 256 blocks
// each kernel, full chip coverage, fully pipelined loads.

#define BATCH   2
#define CH      128
#define NPOS    512
#define GROUPS  32
#define CPG     4               // channels per group = 128/32
#define CHUNKS  4               // position chunks per group
#define CHUNK_N (NPOS / CHUNKS) // 128 positions per chunk
#define GEPS    1e-5f

// Kernel 1: one block per (b, g, chunk). 256 threads = 4 waves; wave j owns
// channel ch0+j, lane owns 2 positions (float2). Computes v = Wv@feat + bv
// for its chunk, stores v to workspace, and one (sum, sumsq) partial per block.
__global__ __launch_bounds__(256) void vproj_kernel(
    const float* __restrict__ feat,    // [B, C, N]
    const float* __restrict__ Wv,      // [C, C]
    const float* __restrict__ bv,      // [C]
    float* __restrict__ vbuf,          // ws: [B, C, N]
    float* __restrict__ partial)       // ws: [B, GROUPS, CHUNKS, 2]
{
    const int blk   = blockIdx.x;         // ((b*GROUPS)+g)*CHUNKS + chunk
    const int chunk = blk & (CHUNKS - 1);
    const int g     = (blk >> 2) & (GROUPS - 1);
    const int b     = blk >> 7;           // / (GROUPS*CHUNKS)
    const int ch0   = g * CPG;
    const int t     = threadIdx.x;
    const int wave  = t >> 6;             // 0..3 == channel offset j
    const int lane  = t & 63;

    __shared__ float w[CPG][CH];          // 2 KB of Wv rows
    __shared__ float red[8];

    // Stage the 4 Wv rows (512 floats, 2 per thread).
    {
        int i = t * 2;
        int j = i >> 7, c = i & (CH - 1);
        w[j][c] = Wv[(ch0 + j) * CH + c];
        ++i; j = i >> 7; c = i & (CH - 1);
        w[j][c] = Wv[(ch0 + j) * CH + c];
    }
    __syncthreads();

    const int j = wave;
    float acc0 = 0.f, acc1 = 0.f;
    // Positions n = chunk*128 + 2*lane, 2*lane+1. Per-wave load = 512 B
    // contiguous; the 4 waves hit the same lines (L1 reuse).
    const float2* fp = reinterpret_cast<const float2*>(
        feat + (size_t)b * CH * NPOS + chunk * CHUNK_N) + lane;
    #pragma unroll 16
    for (int c = 0; c < CH; ++c) {
        float2 f  = fp[c * (NPOS / 2)];   // independent loads, deep ILP
        float  wv = w[j][c];              // LDS broadcast (uniform per wave)
        acc0 = fmaf(wv, f.x, acc0);
        acc1 = fmaf(wv, f.y, acc1);
    }
    const float bias = bv[ch0 + j];
    acc0 += bias;
    acc1 += bias;

    // Store v chunk (coalesced 8 B/lane).
    float2* vp = reinterpret_cast<float2*>(
        vbuf + ((size_t)(b * CH + ch0 + j)) * NPOS + chunk * CHUNK_N) + lane;
    *vp = make_float2(acc0, acc1);

    // Block-level partial (sum, sumsq) over its 512 v-elements.
    float s  = acc0 + acc1;
    float s2 = acc0 * acc0 + acc1 * acc1;
    #pragma unroll
    for (int off = 32; off > 0; off >>= 1) {
        s  += __shfl_down(s, off);
        s2 += __shfl_down(s2, off);
    }
    if (lane == 0) { red[wave] = s; red[wave + 4] = s2; }
    __syncthreads();
    if (t == 0) {
        float S  = red[0] + red[1] + red[2] + red[3];
        float S2 = red[4] + red[5] + red[6] + red[7];
        float* p = partial + (size_t)((b * GROUPS + g) * CHUNKS + chunk) * 2;
        p[0] = S;
        p[1] = S2;
    }
}

// Kernel 2: one block per (b, g, chunk). Reads the group's 4 partials
// (8 uniform scalar loads -> s_load), finalizes stats redundantly, then
// streams normalize + affine + ReLU for its chunk.
__global__ __launch_bounds__(256) void gnorm_kernel(
    const float* __restrict__ vbuf,    // ws: [B, C, N]
    const float* __restrict__ partial, // ws: [B, GROUPS, CHUNKS, 2]
    const float* __restrict__ gam,     // [C]
    const float* __restrict__ bet,     // [C]
    float* __restrict__ out)           // [B, C, N]
{
    const int blk   = blockIdx.x;
    const int chunk = blk & (CHUNKS - 1);
    const int g     = (blk >> 2) & (GROUPS - 1);
    const int b     = blk >> 7;
    const int ch0   = g * CPG;
    const int t     = threadIdx.x;
    const int j     = t >> 6;
    const int lane  = t & 63;

    const float* p = partial + (size_t)((b * GROUPS + g) * CHUNKS) * 2;
    float S  = p[0] + p[2] + p[4] + p[6];
    float S2 = p[1] + p[3] + p[5] + p[7];
    const float inv_n = 1.0f / (float)(CPG * NPOS);   // 1/2048
    float m = S * inv_n;
    float r = rsqrtf(S2 * inv_n - m * m + GEPS);

    const float2* vp = reinterpret_cast<const float2*>(
        vbuf + ((size_t)(b * CH + ch0 + j)) * NPOS + chunk * CHUNK_N) + lane;
    float2 v = *vp;

    float ga = gam[ch0 + j] * r;
    float be = fmaf(-m, ga, bet[ch0 + j]);  // y = v*ga + be
    float2 y;
    y.x = fmaxf(fmaf(v.x, ga, be), 0.0f);
    y.y = fmaxf(fmaf(v.y, ga, be), 0.0f);

    float2* op = reinterpret_cast<float2*>(
        out + ((size_t)(b * CH + ch0 + j)) * NPOS + chunk * CHUNK_N) + lane;
    *op = y;
}

extern "C" void kernel_launch(void* const* d_in, const int* in_sizes, int n_in,
                              void* d_out, int out_size, void* d_ws, size_t ws_size,
                              hipStream_t stream) {
    const float* feat = (const float*)d_in[0];   // [2,128,512]
    const float* Wv   = (const float*)d_in[5];   // [128,128]
    const float* bv   = (const float*)d_in[6];   // [128]
    const float* gng  = (const float*)d_in[7];   // [128]
    const float* gnb  = (const float*)d_in[8];   // [128]
    float* out = (float*)d_out;                  // [2,128,512]

    float* vbuf    = (float*)d_ws;                       // 512 KB
    float* partial = vbuf + (size_t)BATCH * CH * NPOS;   // 2 KB

    const dim3 grid(BATCH * GROUPS * CHUNKS);            // 256 blocks
    const dim3 blockDim3(256);

    vproj_kernel<<<grid, blockDim3, 0, stream>>>(feat, Wv, bv, vbuf, partial);
    gnorm_kernel<<<grid, blockDim3, 0, stream>>>(vbuf, partial, gng, gnb, out);
}